// Round 3
// baseline (820.620 us; speedup 1.0000x reference)
//
#include <hip/hip_runtime.h>
#include <hip/hip_bf16.h>
#include <stdint.h>

// Problem constants (FC_Caps): B=32, I=1024, O=64, D_out=32, D_in=16
#define B_  32
#define I_  1024
#define O_  64
#define D_  32
#define N_  16
#define OD_ 2048   // O_*D_

// ---------- bf16 helpers (bit-exact RNE pack, shift unpack) ----------
__device__ __forceinline__ uint32_t f2bf1(float f) {
  uint32_t u = __float_as_uint(f);
  return (u + 0x7fffu + ((u >> 16) & 1u)) >> 16;
}
__device__ __forceinline__ uint32_t pack2(float a, float b) {
  return f2bf1(a) | (f2bf1(b) << 16);
}
__device__ __forceinline__ void unpack8(uint4 r, float u[8]) {
  u[0] = __uint_as_float(r.x << 16);
  u[1] = __uint_as_float(r.x & 0xffff0000u);
  u[2] = __uint_as_float(r.y << 16);
  u[3] = __uint_as_float(r.y & 0xffff0000u);
  u[4] = __uint_as_float(r.z << 16);
  u[5] = __uint_as_float(r.z & 0xffff0000u);
  u[6] = __uint_as_float(r.w << 16);
  u[7] = __uint_as_float(r.w & 0xffff0000u);
}

// ---------- K1: u_hat[b][i][od] = sum_n W[i,od,n] * x[b,i,n]  (bf16 out) ----------
// Block = (i, od-quarter). Thread owns 2 od rows (32-VGPR W tile, total <=64 ->
// 8 waves/SIMD). Grid 4096. Store: dword (2 bf16) fully coalesced.
__global__ __launch_bounds__(256, 8) void k_einsum(const float* __restrict__ x,
                                                   const float* __restrict__ W,
                                                   uint32_t* __restrict__ uhat) {
  const int i = blockIdx.x >> 2;
  const int q = blockIdx.x & 3;
  const int t = threadIdx.x;
  const int od_base = q * 512 + t * 2;
  __shared__ float xs[B_ * N_];
  for (int e = t; e < B_ * N_; e += 256) {
    int bb = e >> 4, n = e & 15;
    xs[e] = x[(size_t)bb * (I_ * N_) + (size_t)i * N_ + n];
  }
  // W[i, od, n]: thread's 2 rows contiguous (128 floats)
  float w[2][16];
  const float* Wi = W + (size_t)i * (OD_ * N_) + (size_t)od_base * N_;
  #pragma unroll
  for (int k = 0; k < 2; ++k) {
    #pragma unroll
    for (int qq = 0; qq < 4; ++qq) {
      float4 f = ((const float4*)(Wi + k * 16))[qq];
      w[k][qq * 4 + 0] = f.x; w[k][qq * 4 + 1] = f.y;
      w[k][qq * 4 + 2] = f.z; w[k][qq * 4 + 3] = f.w;
    }
  }
  __syncthreads();
  #pragma unroll 4
  for (int bb = 0; bb < B_; ++bb) {
    float4 x0 = ((const float4*)(xs + bb * 16))[0];
    float4 x1 = ((const float4*)(xs + bb * 16))[1];
    float4 x2 = ((const float4*)(xs + bb * 16))[2];
    float4 x3 = ((const float4*)(xs + bb * 16))[3];
    float xv[16] = {x0.x, x0.y, x0.z, x0.w, x1.x, x1.y, x1.z, x1.w,
                    x2.x, x2.y, x2.z, x2.w, x3.x, x3.y, x3.z, x3.w};
    float a0 = 0.f, a1 = 0.f;
    #pragma unroll
    for (int n = 0; n < 16; ++n) {
      a0 = fmaf(w[0][n], xv[n], a0);
      a1 = fmaf(w[1][n], xv[n], a1);
    }
    uhat[(((size_t)bb * I_ + i) * OD_ + od_base) >> 1] = pack2(a0, a1);
  }
}

// ---------- K2: iter-0 weighted sum (c exactly uniform). chunk=16, bf16 partials ----------
__global__ __launch_bounds__(256) void k_sum0(const uint4* __restrict__ uhat,
                                              uint4* __restrict__ part) {
  const int b = blockIdx.x >> 6, chunk = blockIdx.x & 63;
  const int t = threadIdx.x;
  float acc[8] = {0.f, 0.f, 0.f, 0.f, 0.f, 0.f, 0.f, 0.f};
  const size_t ubase = (((size_t)b * I_ + (size_t)chunk * 16) * OD_ + (size_t)t * 8) >> 3;
  #pragma unroll 4
  for (int ii = 0; ii < 16; ++ii) {
    uint4 r = uhat[ubase + (size_t)ii * (OD_ / 8)];
    float u[8]; unpack8(r, u);
    #pragma unroll
    for (int j = 0; j < 8; ++j) acc[j] += u[j];
  }
  part[(((size_t)b * 64 + chunk) * OD_ + (size_t)t * 8) >> 3] =
      make_uint4(pack2(acc[0], acc[1]), pack2(acc[2], acc[3]),
                 pack2(acc[4], acc[5]), pack2(acc[6], acc[7]));
}

// ---------- squash: reduce 64 bf16 chunk-partials, scale, (+bias), squash over d ----------
__global__ __launch_bounds__(256) void k_squash(const uint16_t* __restrict__ part,
                                                const float* __restrict__ bias,
                                                float* __restrict__ vout,
                                                float scale, int addBias) {
  const int lane = threadIdx.x & 63;
  const int row = blockIdx.x * 4 + (threadIdx.x >> 6);  // b=row>>6, o=row&63
  const int b = row >> 6, o = row & 63;
  const int d = lane & 31;
  const uint16_t* p = part + (size_t)b * (64 * OD_) + (size_t)o * 32 + d;
  float s = 0.f;
  const int c0 = (lane >> 5) * 32;   // half-waves split the 64 chunks
  for (int c = c0; c < c0 + 32; ++c)
    s += __uint_as_float(((uint32_t)p[(size_t)c * OD_]) << 16);
  s += __shfl_xor(s, 32);
  s *= scale;
  if (addBias) s += bias[o * 32 + d];
  float dot = s * s;
  #pragma unroll
  for (int off = 1; off <= 16; off <<= 1) dot += __shfl_xor(dot, off);
  float sc = dot / (1.f + dot) / sqrtf(dot + 1e-8f);
  if (lane < 32) vout[(size_t)row * 32 + d] = s * sc;
}

// ---------- routing pass (iters 1 and 2) ----------
// Block = (b, chunk of 16 i). u_hat kept in REGISTERS across phases (no global
// re-read in phase C). Softmax in-place in 4 KB LDS. 2 barriers.
__global__ __launch_bounds__(256, 4) void k_route(const uint4* __restrict__ uhat,
                                                  const float* __restrict__ vprev,
                                                  float* __restrict__ bij,
                                                  uint4* __restrict__ part,
                                                  int secondIter) {
  const int b = blockIdx.x >> 6, chunk = blockIdx.x & 63;
  const int t = threadIdx.x;
  __shared__ float abuf[16 * 64];   // a in phase A/B, overwritten by c in B
  float vreg[8];
  {
    const float4* vp = (const float4*)(vprev + (size_t)b * OD_ + (size_t)t * 8);
    float4 v0 = vp[0], v1 = vp[1];
    vreg[0] = v0.x; vreg[1] = v0.y; vreg[2] = v0.z; vreg[3] = v0.w;
    vreg[4] = v1.x; vreg[5] = v1.y; vreg[6] = v1.z; vreg[7] = v1.w;
  }
  const size_t ubase = (((size_t)b * I_ + (size_t)chunk * 16) * OD_ + (size_t)t * 8) >> 3;
  uint4 u4[16];
  // --- Phase A: load u (stays in regs), agreements -> LDS ---
  #pragma unroll
  for (int ii = 0; ii < 16; ++ii) {
    u4[ii] = uhat[ubase + (size_t)ii * (OD_ / 8)];
    float u[8]; unpack8(u4[ii], u);
    float p = 0.f;
    #pragma unroll
    for (int j = 0; j < 8; ++j) p = fmaf(u[j], vreg[j], p);
    p += __shfl_xor(p, 1);
    p += __shfl_xor(p, 2);
    if ((t & 3) == 0) abuf[ii * 64 + (t >> 2)] = p;
  }
  __syncthreads();
  // --- Phase B: softmax over o per i-row. 16 threads/row, 4 o's each ---
  {
    const int ii = t >> 4;
    const int g = t & 15;
    const int i = chunk * 16 + ii;
    float bn[4];
    const size_t bidx = ((size_t)b * I_ + i) * 64 + g * 4;
    if (secondIter) {
      float4 b0 = *((const float4*)(bij + bidx));
      bn[0] = b0.x + abuf[ii * 64 + g * 4 + 0];
      bn[1] = b0.y + abuf[ii * 64 + g * 4 + 1];
      bn[2] = b0.z + abuf[ii * 64 + g * 4 + 2];
      bn[3] = b0.w + abuf[ii * 64 + g * 4 + 3];
    } else {
      #pragma unroll
      for (int j = 0; j < 4; ++j) bn[j] = abuf[ii * 64 + g * 4 + j];
      *((float4*)(bij + bidx)) = make_float4(bn[0], bn[1], bn[2], bn[3]);
    }
    float m = fmaxf(fmaxf(bn[0], bn[1]), fmaxf(bn[2], bn[3]));
    m = fmaxf(m, __shfl_xor(m, 1));
    m = fmaxf(m, __shfl_xor(m, 2));
    m = fmaxf(m, __shfl_xor(m, 4));
    m = fmaxf(m, __shfl_xor(m, 8));
    float e[4], sm = 0.f;
    #pragma unroll
    for (int j = 0; j < 4; ++j) { e[j] = __expf(bn[j] - m); sm += e[j]; }
    sm += __shfl_xor(sm, 1);
    sm += __shfl_xor(sm, 2);
    sm += __shfl_xor(sm, 4);
    sm += __shfl_xor(sm, 8);
    float inv = 1.f / sm;
    #pragma unroll
    for (int j = 0; j < 4; ++j) abuf[ii * 64 + g * 4 + j] = e[j] * inv;  // c in place
  }
  __syncthreads();
  // --- Phase C: s_acc += c * u (u from regs, c from LDS broadcast) ---
  float s_acc[8] = {0.f, 0.f, 0.f, 0.f, 0.f, 0.f, 0.f, 0.f};
  const int oq = t >> 2;
  #pragma unroll
  for (int ii = 0; ii < 16; ++ii) {
    float u[8]; unpack8(u4[ii], u);
    const float c = abuf[ii * 64 + oq];
    #pragma unroll
    for (int j = 0; j < 8; ++j) s_acc[j] = fmaf(c, u[j], s_acc[j]);
  }
  part[(((size_t)b * 64 + chunk) * OD_ + (size_t)t * 8) >> 3] =
      make_uint4(pack2(s_acc[0], s_acc[1]), pack2(s_acc[2], s_acc[3]),
                 pack2(s_acc[4], s_acc[5]), pack2(s_acc[6], s_acc[7]));
}

extern "C" void kernel_launch(void* const* d_in, const int* in_sizes, int n_in,
                              void* d_out, int out_size, void* d_ws, size_t ws_size,
                              hipStream_t stream) {
  const float* x    = (const float*)d_in[0];  // [32,1024,16]
  const float* W    = (const float*)d_in[1];  // [1,1024,64,32,16]
  const float* bias = (const float*)d_in[2];  // [1,1,64,32]
  float* out = (float*)d_out;                 // [32,64,32]

  char* ws = (char*)d_ws;
  uint32_t* uhat1 = (uint32_t*)ws;                            // 128 MB bf16 u_hat
  uint4*    uhat4 = (uint4*)ws;
  float* bij  = (float*)(ws + 134217728ull);                  // 8 MB  b_ij[b,i,o]
  uint4* part = (uint4*)(ws + 134217728ull + 8388608ull);     // 8 MB  bf16 partials [b,64,od]
  uint16_t* part16 = (uint16_t*)part;
  float* vbuf = (float*)(ws + 134217728ull + 16777216ull);    // 256 KB v[b,od]

  k_einsum<<<dim3(I_ * 4), dim3(256), 0, stream>>>(x, W, uhat1);
  // iter 0: uniform c = 1/64
  k_sum0  <<<dim3(2048), dim3(256), 0, stream>>>(uhat4, part);
  k_squash<<<dim3(512),  dim3(256), 0, stream>>>(part16, bias, vbuf, 1.f / 64.f, 0);
  // iter 1
  k_route <<<dim3(2048), dim3(256), 0, stream>>>(uhat4, vbuf, bij, part, 0);
  k_squash<<<dim3(512),  dim3(256), 0, stream>>>(part16, bias, vbuf, 1.f, 0);
  // iter 2 (last): + bias, output
  k_route <<<dim3(2048), dim3(256), 0, stream>>>(uhat4, vbuf, bij, part, 1);
  k_squash<<<dim3(512),  dim3(256), 0, stream>>>(part16, bias, out, 1.f, 1);
}

// Round 4
// 314.249 us; speedup vs baseline: 2.6114x; 2.6114x over previous
//
#include <hip/hip_runtime.h>
#include <hip/hip_bf16.h>
#include <stdint.h>

// Problem constants (FC_Caps): B=32, I=1024, O=64, D_out=32, D_in=16
#define B_  32
#define I_  1024
#define O_  64
#define D_  32
#define N_  16
#define OD_ 2048   // O_*D_

// ---------- bf16 helpers (bit-exact RNE pack, shift unpack) ----------
__device__ __forceinline__ uint32_t f2bf1(float f) {
  uint32_t u = __float_as_uint(f);
  return (u + 0x7fffu + ((u >> 16) & 1u)) >> 16;
}
__device__ __forceinline__ uint32_t pack2(float a, float b) {
  return f2bf1(a) | (f2bf1(b) << 16);
}
__device__ __forceinline__ void unpack8(uint4 r, float u[8]) {
  u[0] = __uint_as_float(r.x << 16);
  u[1] = __uint_as_float(r.x & 0xffff0000u);
  u[2] = __uint_as_float(r.y << 16);
  u[3] = __uint_as_float(r.y & 0xffff0000u);
  u[4] = __uint_as_float(r.z << 16);
  u[5] = __uint_as_float(r.z & 0xffff0000u);
  u[6] = __uint_as_float(r.w << 16);
  u[7] = __uint_as_float(r.w & 0xffff0000u);
}

// ---------- K1: u_hat[b][i][od] = sum_n W[i,od,n] * x[b,i,n]  (bf16 out) ----------
// Block = (i, od-quarter). Thread owns W rows od0 and od0+256 (one row = 64 B =
// exactly one cache line per lane; lane stride 64 B; each line fully consumed
// by this wave's own 4 loads -> fetch efficiency independent of occupancy).
// Stores: ushort per lane, 128 B contiguous per wave instruction (full lines).
__global__ __launch_bounds__(256) void k_einsum(const float* __restrict__ x,
                                                const float* __restrict__ W,
                                                uint16_t* __restrict__ uhat) {
  const int i = blockIdx.x >> 2;
  const int q = blockIdx.x & 3;
  const int t = threadIdx.x;
  const int od0 = q * 512 + t;          // row A; row B = od0 + 256
  __shared__ float xs[B_ * N_];
  for (int e = t; e < B_ * N_; e += 256) {
    int bb = e >> 4, n = e & 15;
    xs[e] = x[(size_t)bb * (I_ * N_) + (size_t)i * N_ + n];
  }
  float wA[16], wB[16];
  {
    const float4* Wa = (const float4*)(W + (size_t)i * (OD_ * N_) + (size_t)od0 * N_);
    const float4* Wb = (const float4*)(W + (size_t)i * (OD_ * N_) + (size_t)(od0 + 256) * N_);
    #pragma unroll
    for (int qq = 0; qq < 4; ++qq) {
      float4 fa = Wa[qq];
      wA[qq * 4 + 0] = fa.x; wA[qq * 4 + 1] = fa.y;
      wA[qq * 4 + 2] = fa.z; wA[qq * 4 + 3] = fa.w;
      float4 fb = Wb[qq];
      wB[qq * 4 + 0] = fb.x; wB[qq * 4 + 1] = fb.y;
      wB[qq * 4 + 2] = fb.z; wB[qq * 4 + 3] = fb.w;
    }
  }
  __syncthreads();
  #pragma unroll 2
  for (int bb = 0; bb < B_; ++bb) {
    float4 x0 = ((const float4*)(xs + bb * 16))[0];   // LDS broadcast reads
    float4 x1 = ((const float4*)(xs + bb * 16))[1];
    float4 x2 = ((const float4*)(xs + bb * 16))[2];
    float4 x3 = ((const float4*)(xs + bb * 16))[3];
    float xv[16] = {x0.x, x0.y, x0.z, x0.w, x1.x, x1.y, x1.z, x1.w,
                    x2.x, x2.y, x2.z, x2.w, x3.x, x3.y, x3.z, x3.w};
    float a0 = 0.f, a1 = 0.f;
    #pragma unroll
    for (int n = 0; n < 16; ++n) {
      a0 = fmaf(wA[n], xv[n], a0);
      a1 = fmaf(wB[n], xv[n], a1);
    }
    const size_t base = ((size_t)bb * I_ + i) * OD_ + od0;
    uhat[base]       = (uint16_t)f2bf1(a0);
    uhat[base + 256] = (uint16_t)f2bf1(a1);
  }
}

// ---------- K2: iter-0 weighted sum (c exactly uniform). chunk=16, bf16 partials ----------
__global__ __launch_bounds__(256) void k_sum0(const uint4* __restrict__ uhat,
                                              uint4* __restrict__ part) {
  const int b = blockIdx.x >> 6, chunk = blockIdx.x & 63;
  const int t = threadIdx.x;
  float acc[8] = {0.f, 0.f, 0.f, 0.f, 0.f, 0.f, 0.f, 0.f};
  const size_t ubase = (((size_t)b * I_ + (size_t)chunk * 16) * OD_ + (size_t)t * 8) >> 3;
  #pragma unroll 4
  for (int ii = 0; ii < 16; ++ii) {
    uint4 r = uhat[ubase + (size_t)ii * (OD_ / 8)];
    float u[8]; unpack8(r, u);
    #pragma unroll
    for (int j = 0; j < 8; ++j) acc[j] += u[j];
  }
  part[(((size_t)b * 64 + chunk) * OD_ + (size_t)t * 8) >> 3] =
      make_uint4(pack2(acc[0], acc[1]), pack2(acc[2], acc[3]),
                 pack2(acc[4], acc[5]), pack2(acc[6], acc[7]));
}

// ---------- squash: reduce 64 bf16 chunk-partials, scale, (+bias), squash over d ----------
__global__ __launch_bounds__(256) void k_squash(const uint16_t* __restrict__ part,
                                                const float* __restrict__ bias,
                                                float* __restrict__ vout,
                                                float scale, int addBias) {
  const int lane = threadIdx.x & 63;
  const int row = blockIdx.x * 4 + (threadIdx.x >> 6);  // b=row>>6, o=row&63
  const int b = row >> 6, o = row & 63;
  const int d = lane & 31;
  const uint16_t* p = part + (size_t)b * (64 * OD_) + (size_t)o * 32 + d;
  float s = 0.f;
  const int c0 = (lane >> 5) * 32;   // half-waves split the 64 chunks
  for (int c = c0; c < c0 + 32; ++c)
    s += __uint_as_float(((uint32_t)p[(size_t)c * OD_]) << 16);
  s += __shfl_xor(s, 32);
  s *= scale;
  if (addBias) s += bias[o * 32 + d];
  float dot = s * s;
  #pragma unroll
  for (int off = 1; off <= 16; off <<= 1) dot += __shfl_xor(dot, off);
  float sc = dot / (1.f + dot) / sqrtf(dot + 1e-8f);
  if (lane < 32) vout[(size_t)row * 32 + d] = s * sc;
}

// ---------- routing pass (iters 1 and 2) ----------
// Block = (b, chunk of 16 i). u_hat kept in REGISTERS across phases (no global
// re-read in phase C). Softmax in-place in 4 KB LDS. 2 barriers.
__global__ __launch_bounds__(256, 4) void k_route(const uint4* __restrict__ uhat,
                                                  const float* __restrict__ vprev,
                                                  float* __restrict__ bij,
                                                  uint4* __restrict__ part,
                                                  int secondIter) {
  const int b = blockIdx.x >> 6, chunk = blockIdx.x & 63;
  const int t = threadIdx.x;
  __shared__ float abuf[16 * 64];   // a in phase A/B, overwritten by c in B
  float vreg[8];
  {
    const float4* vp = (const float4*)(vprev + (size_t)b * OD_ + (size_t)t * 8);
    float4 v0 = vp[0], v1 = vp[1];
    vreg[0] = v0.x; vreg[1] = v0.y; vreg[2] = v0.z; vreg[3] = v0.w;
    vreg[4] = v1.x; vreg[5] = v1.y; vreg[6] = v1.z; vreg[7] = v1.w;
  }
  const size_t ubase = (((size_t)b * I_ + (size_t)chunk * 16) * OD_ + (size_t)t * 8) >> 3;
  uint4 u4[16];
  // --- Phase A: load u (stays in regs), agreements -> LDS ---
  #pragma unroll
  for (int ii = 0; ii < 16; ++ii) {
    u4[ii] = uhat[ubase + (size_t)ii * (OD_ / 8)];
    float u[8]; unpack8(u4[ii], u);
    float p = 0.f;
    #pragma unroll
    for (int j = 0; j < 8; ++j) p = fmaf(u[j], vreg[j], p);
    p += __shfl_xor(p, 1);
    p += __shfl_xor(p, 2);
    if ((t & 3) == 0) abuf[ii * 64 + (t >> 2)] = p;
  }
  __syncthreads();
  // --- Phase B: softmax over o per i-row. 16 threads/row, 4 o's each ---
  {
    const int ii = t >> 4;
    const int g = t & 15;
    const int i = chunk * 16 + ii;
    float bn[4];
    const size_t bidx = ((size_t)b * I_ + i) * 64 + g * 4;
    if (secondIter) {
      float4 b0 = *((const float4*)(bij + bidx));
      bn[0] = b0.x + abuf[ii * 64 + g * 4 + 0];
      bn[1] = b0.y + abuf[ii * 64 + g * 4 + 1];
      bn[2] = b0.z + abuf[ii * 64 + g * 4 + 2];
      bn[3] = b0.w + abuf[ii * 64 + g * 4 + 3];
    } else {
      #pragma unroll
      for (int j = 0; j < 4; ++j) bn[j] = abuf[ii * 64 + g * 4 + j];
      *((float4*)(bij + bidx)) = make_float4(bn[0], bn[1], bn[2], bn[3]);
    }
    float m = fmaxf(fmaxf(bn[0], bn[1]), fmaxf(bn[2], bn[3]));
    m = fmaxf(m, __shfl_xor(m, 1));
    m = fmaxf(m, __shfl_xor(m, 2));
    m = fmaxf(m, __shfl_xor(m, 4));
    m = fmaxf(m, __shfl_xor(m, 8));
    float e[4], sm = 0.f;
    #pragma unroll
    for (int j = 0; j < 4; ++j) { e[j] = __expf(bn[j] - m); sm += e[j]; }
    sm += __shfl_xor(sm, 1);
    sm += __shfl_xor(sm, 2);
    sm += __shfl_xor(sm, 4);
    sm += __shfl_xor(sm, 8);
    float inv = 1.f / sm;
    #pragma unroll
    for (int j = 0; j < 4; ++j) abuf[ii * 64 + g * 4 + j] = e[j] * inv;  // c in place
  }
  __syncthreads();
  // --- Phase C: s_acc += c * u (u from regs, c from LDS broadcast) ---
  float s_acc[8] = {0.f, 0.f, 0.f, 0.f, 0.f, 0.f, 0.f, 0.f};
  const int oq = t >> 2;
  #pragma unroll
  for (int ii = 0; ii < 16; ++ii) {
    float u[8]; unpack8(u4[ii], u);
    const float c = abuf[ii * 64 + oq];
    #pragma unroll
    for (int j = 0; j < 8; ++j) s_acc[j] = fmaf(c, u[j], s_acc[j]);
  }
  part[(((size_t)b * 64 + chunk) * OD_ + (size_t)t * 8) >> 3] =
      make_uint4(pack2(s_acc[0], s_acc[1]), pack2(s_acc[2], s_acc[3]),
                 pack2(s_acc[4], s_acc[5]), pack2(s_acc[6], s_acc[7]));
}

extern "C" void kernel_launch(void* const* d_in, const int* in_sizes, int n_in,
                              void* d_out, int out_size, void* d_ws, size_t ws_size,
                              hipStream_t stream) {
  const float* x    = (const float*)d_in[0];  // [32,1024,16]
  const float* W    = (const float*)d_in[1];  // [1,1024,64,32,16]
  const float* bias = (const float*)d_in[2];  // [1,1,64,32]
  float* out = (float*)d_out;                 // [32,64,32]

  char* ws = (char*)d_ws;
  uint16_t* uhat1 = (uint16_t*)ws;                            // 128 MB bf16 u_hat
  uint4*    uhat4 = (uint4*)ws;
  float* bij  = (float*)(ws + 134217728ull);                  // 8 MB  b_ij[b,i,o]
  uint4* part = (uint4*)(ws + 134217728ull + 8388608ull);     // 8 MB  bf16 partials [b,64,od]
  uint16_t* part16 = (uint16_t*)part;
  float* vbuf = (float*)(ws + 134217728ull + 16777216ull);    // 256 KB v[b,od]

  k_einsum<<<dim3(I_ * 4), dim3(256), 0, stream>>>(x, W, uhat1);
  // iter 0: uniform c = 1/64
  k_sum0  <<<dim3(2048), dim3(256), 0, stream>>>(uhat4, part);
  k_squash<<<dim3(512),  dim3(256), 0, stream>>>(part16, bias, vbuf, 1.f / 64.f, 0);
  // iter 1
  k_route <<<dim3(2048), dim3(256), 0, stream>>>(uhat4, vbuf, bij, part, 0);
  k_squash<<<dim3(512),  dim3(256), 0, stream>>>(part16, bias, vbuf, 1.f, 0);
  // iter 2 (last): + bias, output
  k_route <<<dim3(2048), dim3(256), 0, stream>>>(uhat4, vbuf, bij, part, 1);
  k_squash<<<dim3(512),  dim3(256), 0, stream>>>(part16, bias, out, 1.f, 1);
}